// Round 11
// baseline (119.097 us; speedup 1.0000x reference)
//
#include <hip/hip_runtime.h>
#include <hip/hip_fp16.h>
#include <math.h>

// Problem constants (fixed by reference setup_inputs)
#define BB 4096
#define LL 16
#define DD 512

// Marginal lookup table: 16 latents x NPTS points over [XMIN, XMIN+XRANGE]
#define NPTS   1024
#define XMIN   -6.0f
#define XRANGE 12.0f

#define LOG2E_F  1.4426950408889634f
#define LN2_F    0.6931471805599453f
#define LOG2PI_F 1.8378770664093453f

// Schraudolph f32 exp2 for the joint: w = 2^23*(lp2sum + BIASF); cvt_u32
// saturates negatives to 0; bits reinterpreted as f32 ~ 2^lp2sum.
#define OFFC     22.942540f
#define SCALE23  8388608.0f
#define BIASF    126.94269504f

#if __has_builtin(__builtin_amdgcn_exp2f)
#define EXP2(x) __builtin_amdgcn_exp2f(x)
#else
#define EXP2(x) exp2f(x)
#endif
#if __has_builtin(__builtin_amdgcn_logf)
#define LOG2(x) __builtin_amdgcn_logf(x)
#else
#define LOG2(x) log2f(x)
#endif

typedef float f32x2 __attribute__((ext_vector_type(2)));

// ws float layout:
//   cj   [0      , 147456)  4096 j * 36: A[16] B[16] Csum pad3 (S-scaled)
//   ct   [147456 , 344064)  raw coefs transposed [part 3][l 16][j 4096]
//   rp   [344064 , 346112)  2048 recon block partials (pre-scaled)
//   klp  [346112 , 346368)  256 KL block partials (pre-scaled)
//   tp   [346368 , 870656)  table partials [jc 32][l 16][g 1024]
//   tab  [870656 , 887040)  marginal table [l 16][g 1024]
//   jp   [887040 , 1411328) joint partials [chunk 128][i 4096]
#define CJ_F   0
#define CT_F   147456
#define RP_F   344064
#define KLP_F  346112
#define TP_F   346368
#define TAB_F  870656
#define JP_F   887040

// Block-level sum reduction; result valid on thread 0. Re-entrant.
__device__ __forceinline__ float block_reduce(float v) {
  __shared__ float sm[4];
  __syncthreads();
#pragma unroll
  for (int off = 32; off; off >>= 1) v += __shfl_xor(v, off);
  if ((threadIdx.x & 63) == 0) sm[threadIdx.x >> 6] = v;
  __syncthreads();
  if (threadIdx.x == 0) v = (sm[0] + sm[1]) + (sm[2] + sm[3]);
  return v;
}

// ---------------------------------------------------------------------------
// Kernel A: recon partials + KL partials + out zero + BOTH coef layouts:
//   joint (S-scaled, per-j Csum via 16-lane shfl reduce):
//     cj[j][0..15]=a*S, [16..31]=-2am*S, [32]=sum_l (a m^2 + c2 + OFFC)*S
//   table-build (raw, transposed): ct[p][l][j] = {a, -2am, a m^2 + c2}
//   lp2(x; j,l) = a x^2 - 2am x + (a m^2 + c2)   [log2-domain density]
// ---------------------------------------------------------------------------
__global__ __launch_bounds__(256) void prep_recon_kernel(
    const float4* __restrict__ data4, const float4* __restrict__ recon4,
    const float* __restrict__ zm, const float* __restrict__ zlv,
    float* __restrict__ cj, float* __restrict__ ct,
    float* __restrict__ rp, float* __restrict__ klp,
    float* __restrict__ out) {
  const int tid = threadIdx.x;
  const int b = blockIdx.x;

  if (b == 1024 && tid == 0) out[0] = 0.0f;  // consumed by final_kernel later

  {
    const int n4 = (BB * DD) / 4;
    int stride = gridDim.x * 256;
    float s = 0.0f;
    for (int k = b * 256 + tid; k < n4; k += stride) {
      float4 a = data4[k];
      float4 r = recon4[k];
      s += (fabsf(a.x - r.x) + fabsf(a.y - r.y)) +
           (fabsf(a.z - r.z) + fabsf(a.w - r.w));
    }
    float t = block_reduce(s);
    if (tid == 0) rp[b] = t * (1.0f / (float)(BB * DD));
  }

  if (b < 256) {
    const float S = 1024.0f / 65535.0f;
    int idx = b * 256 + tid;
    int j = idx >> 4;
    int l = idx & 15;
    float m = zm[idx];
    float lv = zlv[idx];
    float inv = EXP2(-lv * LOG2E_F);           // e^{-lv}
    float a = -0.5f * LOG2E_F * inv;           // log2-domain quadratic coef
    float c2 = -0.5f * LOG2E_F * (lv + LOG2PI_F);
    float braw = -2.0f * a * m;
    float craw = fmaf(a, m * m, c2);

    cj[j * 36 + l]      = a * S;
    cj[j * 36 + 16 + l] = braw * S;
    float cs = (craw + OFFC) * S;
    // per-j sum of cS over the 16 latents (lanes of one j are contiguous)
    cs += __shfl_xor(cs, 1); cs += __shfl_xor(cs, 2);
    cs += __shfl_xor(cs, 4); cs += __shfl_xor(cs, 8);
    if (l == 0) cj[j * 36 + 32] = cs;

    ct[(0 * 16 + l) * 4096 + j] = a;
    ct[(1 * 16 + l) * 4096 + j] = braw;
    ct[(2 * 16 + l) * 4096 + j] = craw;

    float kls = m * m + EXP2(lv * LOG2E_F) - lv - 1.0f;
    float s = block_reduce(kls);
    if (tid == 0) klp[b] = s * (0.5f / (float)BB);
  }
}

// ---------------------------------------------------------------------------
// Kernel B1: marginal table build. g_l(x) = sum_j 2^(lp2(x; j,l)) sampled at
// NPTS points, EXACT v_exp_f32 (more accurate than the old f16-Schraudolph
// marginal path). grid (32 jc, 16 l) = 512 blocks; each block: 1/32 of j,
// all 1024 points (4 per thread); partials summed by table_reduce.
// ---------------------------------------------------------------------------
__global__ __launch_bounds__(256) void table_build(
    const float* __restrict__ ct, float* __restrict__ tpart) {
  __shared__ float la[128], lb[128], lc[128];
  const int tid = threadIdx.x;
  const int jc = blockIdx.x;   // 0..31
  const int l  = blockIdx.y;   // 0..15
  const int j0 = jc * 128;
  if (tid < 128) {
    la[tid] = ct[(0 * 16 + l) * 4096 + j0 + tid];
    lb[tid] = ct[(1 * 16 + l) * 4096 + j0 + tid];
    lc[tid] = ct[(2 * 16 + l) * 4096 + j0 + tid];
  }
  const float H = XRANGE / (float)(NPTS - 1);
  float x[4], acc[4];
#pragma unroll
  for (int k = 0; k < 4; ++k) {
    x[k] = XMIN + (float)(k * 256 + tid) * H;
    acc[k] = 0.0f;
  }
  __syncthreads();
#pragma unroll 2
  for (int j = 0; j < 128; ++j) {
    float a = la[j], b = lb[j], c = lc[j];  // wave-uniform LDS broadcast
#pragma unroll
    for (int k = 0; k < 4; ++k) {
      float lp = fmaf(fmaf(a, x[k], b), x[k], c);
      acc[k] += EXP2(lp);
    }
  }
  float* o = tpart + ((size_t)jc * 16 + l) * NPTS;
#pragma unroll
  for (int k = 0; k < 4; ++k) o[k * 256 + tid] = acc[k];
}

// ---------------------------------------------------------------------------
// Kernel B2: sum the 32 jc-partials -> table[l][g]. grid 64 blocks.
// ---------------------------------------------------------------------------
__global__ __launch_bounds__(256) void table_reduce(
    const float* __restrict__ tpart, float* __restrict__ table) {
  const int e = blockIdx.x * 256 + threadIdx.x;  // 0..16383
  float s = 0.0f;
#pragma unroll 4
  for (int jc = 0; jc < 32; ++jc) s += tpart[(size_t)jc * (16 * NPTS) + e];
  table[e] = s;
}

// ---------------------------------------------------------------------------
// Kernel C: JOINT-only TC pass (marginals now come from the table).
// Per pair: 16 v_pk_fma (sum_l (A z + B) z) + Csum + Schraudolph cvt_u32.
// ~99 instr/j (vs ~185 with marginals), 9 ds_reads/j (vs 12). R=4 rows,
// CHUNK=32, grid (4,128)=512 blocks = 2/CU (R10-proven shape). Output:
// jp[chunk][i] f32 = 2 MB (was 18.9 MB packed partials).
// ---------------------------------------------------------------------------
template <int CHUNK, int R>
__global__ __launch_bounds__(256, 2) void tc_joint(
    const float* __restrict__ z, const float* __restrict__ cj,
    float* __restrict__ jp) {
  __shared__ float lcj[CHUNK * 36];
  const int tid = threadIdx.x;
  const int i0 = blockIdx.x * (256 * R) + tid;
  const int j0 = blockIdx.y * CHUNK;
  const float JMUL = 65535.0f * 8192.0f;
  const float JK   = -SCALE23 * (16.0f * OFFC - BIASF);

  {
    const float4* g4 = (const float4*)(cj + (size_t)j0 * 36);
    float4* l4 = (float4*)lcj;
    for (int t = tid; t < (CHUNK * 36) / 4; t += 256) l4[t] = g4[t];
  }

  f32x2 zv[R][8];
#pragma unroll
  for (int r = 0; r < R; ++r) {
    const float4* zp = (const float4*)(z + (size_t)(i0 + 256 * r) * 16);
#pragma unroll
    for (int q = 0; q < 4; ++q) {
      float4 v = zp[q];
      zv[r][2 * q]     = (f32x2){v.x, v.y};
      zv[r][2 * q + 1] = (f32x2){v.z, v.w};
    }
  }
  // Pin: compiler otherwise sinks z loads into the j-loop (R4 lesson).
#pragma unroll
  for (int r = 0; r < R; ++r)
#pragma unroll
    for (int p = 0; p < 8; ++p) asm volatile("" : "+v"(zv[r][p]));

  float accJ[R];
#pragma unroll
  for (int r = 0; r < R; ++r) accJ[r] = 0.0f;

  __syncthreads();

#pragma unroll 2
  for (int j = 0; j < CHUNK; ++j) {
    const float* cp = lcj + j * 36;
    f32x2 A[8], Bv[8];
#pragma unroll
    for (int t = 0; t < 4; ++t) {  // 8x ds_read_b128
      *(float4*)&A[2 * t]  = *(const float4*)(cp + 4 * t);
      *(float4*)&Bv[2 * t] = *(const float4*)(cp + 16 + 4 * t);
    }
    float Cs = cp[32];             // 1x ds_read_b32
#pragma unroll
    for (int r = 0; r < R; ++r) {
      f32x2 acc = (f32x2){0.0f, 0.0f};
#pragma unroll
      for (int p = 0; p < 8; ++p) {
        f32x2 t2 = __builtin_elementwise_fma(A[p], zv[r][p], Bv[p]);
        acc = __builtin_elementwise_fma(t2, zv[r][p], acc);  // 2x v_pk_fma
      }
      float js = (acc.x + acc.y) + Cs;   // S*(sum_l lp2 + 16*OFFC)
      float w = fmaf(js, JMUL, JK);      // 2^23*(sum lp2 + BIASF)
      unsigned u;
      asm("v_cvt_u32_f32 %0, %1" : "=v"(u) : "v"(w));  // neg saturates to 0
      accJ[r] += __uint_as_float(u);
    }
  }

#pragma unroll
  for (int r = 0; r < R; ++r)
    jp[(size_t)blockIdx.y * BB + (size_t)(i0 + 256 * r)] = accJ[r];
}

// ---------------------------------------------------------------------------
// Kernel D: final. Sums joint partials (128 planes), stages the 64 KB table
// in LDS, interpolates the 16 marginals per i, logs, folds recon/KL.
// LDS is reused for the block reduction after the gathers complete.
// ---------------------------------------------------------------------------
__global__ __launch_bounds__(256) void final_kernel(
    const float* __restrict__ z, const float* __restrict__ jp,
    const float* __restrict__ table, const float* __restrict__ rp,
    const float* __restrict__ klp, float* __restrict__ out, int nc) {
  __shared__ float ltab[16 * NPTS];  // 64 KB
  const int tid = threadIdx.x;
  const int i = blockIdx.x * 256 + tid;

  for (int t = tid; t < 16 * NPTS; t += 256) ltab[t] = table[t];

  float s0 = 0.0f, s1 = 0.0f, s2 = 0.0f, s3 = 0.0f;
  for (int c = 0; c < nc; c += 4) {
    s0 += jp[(size_t)(c + 0) * BB + i];
    s1 += jp[(size_t)(c + 1) * BB + i];
    s2 += jp[(size_t)(c + 2) * BB + i];
    s3 += jp[(size_t)(c + 3) * BB + i];
  }
  float lg = LOG2((s0 + s1) + (s2 + s3));  // log2 S_joint

  __syncthreads();  // table staged

  const float4* zp = (const float4*)(z + (size_t)i * 16);
  const float SC = (float)(NPTS - 1) / XRANGE;
#pragma unroll
  for (int q = 0; q < 4; ++q) {
    float4 v = zp[q];
    float xs[4] = {v.x, v.y, v.z, v.w};
#pragma unroll
    for (int k = 0; k < 4; ++k) {
      int l = 4 * q + k;
      float t = (xs[k] - XMIN) * SC;
      t = fminf(fmaxf(t, 0.0f), (float)(NPTS - 2) + 0.999f);
      int g = (int)t;
      float f = t - (float)g;
      float m0 = ltab[l * NPTS + g];
      float m1 = ltab[l * NPTS + g + 1];
      lg -= LOG2(fmaf(f, m1 - m0, m0));
    }
  }

  float tval = lg * (LN2_F / (float)BB);
  if (blockIdx.x == 0) {
#pragma unroll
    for (int q = 0; q < 8; ++q) tval += rp[tid + 256 * q];
    tval += klp[tid];
  }

  __syncthreads();  // all gathers done; safe to reuse ltab
#pragma unroll
  for (int off = 32; off; off >>= 1) tval += __shfl_xor(tval, off);
  if ((tid & 63) == 0) ltab[tid >> 6] = tval;
  __syncthreads();
  if (tid == 0) atomicAdd(out, (ltab[0] + ltab[1]) + (ltab[2] + ltab[3]));
}

extern "C" void kernel_launch(void* const* d_in, const int* in_sizes, int n_in,
                              void* d_out, int out_size, void* d_ws, size_t ws_size,
                              hipStream_t stream) {
  const float* data  = (const float*)d_in[0];
  const float* recon = (const float*)d_in[1];
  const float* z     = (const float*)d_in[2];
  const float* zm    = (const float*)d_in[3];
  const float* zlv   = (const float*)d_in[4];
  float* out = (float*)d_out;
  float* ws  = (float*)d_ws;

  const int nc = 128;  // joint chunks: CHUNK=32, grid (4,128) = 512 = 2/CU

  float* cj   = ws + CJ_F;
  float* ct   = ws + CT_F;
  float* rp   = ws + RP_F;
  float* klp  = ws + KLP_F;
  float* tp   = ws + TP_F;
  float* tab  = ws + TAB_F;
  float* jp   = ws + JP_F;

  hipLaunchKernelGGL(prep_recon_kernel, dim3(2048), dim3(256), 0, stream,
                     reinterpret_cast<const float4*>(data),
                     reinterpret_cast<const float4*>(recon),
                     zm, zlv, cj, ct, rp, klp, out);
  hipLaunchKernelGGL(table_build, dim3(32, 16), dim3(256), 0, stream,
                     ct, tp);
  hipLaunchKernelGGL(table_reduce, dim3((16 * NPTS) / 256), dim3(256), 0,
                     stream, tp, tab);
  hipLaunchKernelGGL((tc_joint<32, 4>), dim3(4, 128), dim3(256), 0, stream,
                     z, cj, jp);
  hipLaunchKernelGGL(final_kernel, dim3(BB / 256), dim3(256), 0, stream,
                     z, jp, tab, rp, klp, out, nc);
}

// Round 13
// 117.908 us; speedup vs baseline: 1.0101x; 1.0101x over previous
//
#include <hip/hip_runtime.h>
#include <hip/hip_fp16.h>
#include <math.h>

// Problem constants (fixed by reference setup_inputs)
#define BB 4096
#define LL 16
#define DD 512

// Marginal lookup table: 16 latents x NPTS points over [XMIN, XMIN+XRANGE]
#define NPTS   1024
#define XMIN   -6.0f
#define XRANGE 12.0f

#define LOG2E_F  1.4426950408889634f
#define LN2_F    0.6931471805599453f
#define LOG2PI_F 1.8378770664093453f

// Schraudolph f32 exp2 for the joint: w = 2^23*(lp2sum + BIASF); cvt_u32
// saturates negatives to 0; bits reinterpreted as f32 ~ 2^lp2sum.
#define OFFC     22.942540f
#define SCALE23  8388608.0f
#define BIASF    126.94269504f

#if __has_builtin(__builtin_amdgcn_exp2f)
#define EXP2(x) __builtin_amdgcn_exp2f(x)
#else
#define EXP2(x) exp2f(x)
#endif
#if __has_builtin(__builtin_amdgcn_logf)
#define LOG2(x) __builtin_amdgcn_logf(x)
#else
#define LOG2(x) log2f(x)
#endif

typedef float f32x2 __attribute__((ext_vector_type(2)));

// ws float layout:
//   cj   [0      , 147456)  4096 j * 36: A[16] B[16] Csum pad3 (S-scaled)
//   ct   [147456 , 344064)  raw coefs transposed [part 3][l 16][j 4096]
//   rp   [344064 , 346112)  2048 recon block partials (pre-scaled)
//   klp  [346112 , 346368)  256 KL block partials (pre-scaled)
//   tp   [346368 , 870656)  table partials [jc 32][l 16][g 1024]
//   tab  [870656 , 887040)  marginal table [l 16][g 1024]
//   jp   [887040 , 1411328) joint partials [chunk 128][i 4096]
#define CJ_F   0
#define CT_F   147456
#define RP_F   344064
#define KLP_F  346112
#define TP_F   346368
#define TAB_F  870656
#define JP_F   887040

// Block-level sum reduction; result valid on thread 0. Re-entrant.
__device__ __forceinline__ float block_reduce(float v) {
  __shared__ float sm[4];
  __syncthreads();
#pragma unroll
  for (int off = 32; off; off >>= 1) v += __shfl_xor(v, off);
  if ((threadIdx.x & 63) == 0) sm[threadIdx.x >> 6] = v;
  __syncthreads();
  if (threadIdx.x == 0) v = (sm[0] + sm[1]) + (sm[2] + sm[3]);
  return v;
}

// ---------------------------------------------------------------------------
// Kernel A: recon partials + KL partials + out zero + both coef layouts.
// ---------------------------------------------------------------------------
__global__ __launch_bounds__(256) void prep_recon_kernel(
    const float4* __restrict__ data4, const float4* __restrict__ recon4,
    const float* __restrict__ zm, const float* __restrict__ zlv,
    float* __restrict__ cj, float* __restrict__ ct,
    float* __restrict__ rp, float* __restrict__ klp,
    float* __restrict__ out) {
  const int tid = threadIdx.x;
  const int b = blockIdx.x;

  if (b == 1024 && tid == 0) out[0] = 0.0f;  // consumed by final_kernel later

  {
    const int n4 = (BB * DD) / 4;
    int stride = gridDim.x * 256;
    float s = 0.0f;
    for (int k = b * 256 + tid; k < n4; k += stride) {
      float4 a = data4[k];
      float4 r = recon4[k];
      s += (fabsf(a.x - r.x) + fabsf(a.y - r.y)) +
           (fabsf(a.z - r.z) + fabsf(a.w - r.w));
    }
    float t = block_reduce(s);
    if (tid == 0) rp[b] = t * (1.0f / (float)(BB * DD));
  }

  if (b < 256) {
    const float S = 1024.0f / 65535.0f;
    int idx = b * 256 + tid;
    int j = idx >> 4;
    int l = idx & 15;
    float m = zm[idx];
    float lv = zlv[idx];
    float inv = EXP2(-lv * LOG2E_F);           // e^{-lv}
    float a = -0.5f * LOG2E_F * inv;           // log2-domain quadratic coef
    float c2 = -0.5f * LOG2E_F * (lv + LOG2PI_F);
    float braw = -2.0f * a * m;
    float craw = fmaf(a, m * m, c2);

    cj[j * 36 + l]      = a * S;
    cj[j * 36 + 16 + l] = braw * S;
    float cs = (craw + OFFC) * S;
    cs += __shfl_xor(cs, 1); cs += __shfl_xor(cs, 2);
    cs += __shfl_xor(cs, 4); cs += __shfl_xor(cs, 8);
    if (l == 0) cj[j * 36 + 32] = cs;

    ct[(0 * 16 + l) * 4096 + j] = a;
    ct[(1 * 16 + l) * 4096 + j] = braw;
    ct[(2 * 16 + l) * 4096 + j] = craw;

    float kls = m * m + EXP2(lv * LOG2E_F) - lv - 1.0f;
    float s = block_reduce(kls);
    if (tid == 0) klp[b] = s * (0.5f / (float)BB);
  }
}

// ---------------------------------------------------------------------------
// Kernel B1: marginal table build (exact v_exp_f32). grid (32 jc, 16 l).
// ---------------------------------------------------------------------------
__global__ __launch_bounds__(256) void table_build(
    const float* __restrict__ ct, float* __restrict__ tpart) {
  __shared__ float la[128], lb[128], lc[128];
  const int tid = threadIdx.x;
  const int jc = blockIdx.x;   // 0..31
  const int l  = blockIdx.y;   // 0..15
  const int j0 = jc * 128;
  if (tid < 128) {
    la[tid] = ct[(0 * 16 + l) * 4096 + j0 + tid];
    lb[tid] = ct[(1 * 16 + l) * 4096 + j0 + tid];
    lc[tid] = ct[(2 * 16 + l) * 4096 + j0 + tid];
  }
  const float H = XRANGE / (float)(NPTS - 1);
  float x[4], acc[4];
#pragma unroll
  for (int k = 0; k < 4; ++k) {
    x[k] = XMIN + (float)(k * 256 + tid) * H;
    acc[k] = 0.0f;
  }
  __syncthreads();
#pragma unroll 2
  for (int j = 0; j < 128; ++j) {
    float a = la[j], b = lb[j], c = lc[j];
#pragma unroll
    for (int k = 0; k < 4; ++k) {
      float lp = fmaf(fmaf(a, x[k], b), x[k], c);
      acc[k] += EXP2(lp);
    }
  }
  float* o = tpart + ((size_t)jc * 16 + l) * NPTS;
#pragma unroll
  for (int k = 0; k < 4; ++k) o[k * 256 + tid] = acc[k];
}

// ---------------------------------------------------------------------------
// Kernel B2: sum the 32 jc-partials -> table[l][g]. grid 64 blocks.
// ---------------------------------------------------------------------------
__global__ __launch_bounds__(256) void table_reduce(
    const float* __restrict__ tpart, float* __restrict__ table) {
  const int e = blockIdx.x * 256 + threadIdx.x;
  float s = 0.0f;
#pragma unroll 4
  for (int jc = 0; jc < 32; ++jc) s += tpart[(size_t)jc * (16 * NPTS) + e];
  table[e] = s;
}

// ---------------------------------------------------------------------------
// Kernel C: JOINT pass with EXPLICIT v_pk_fma_f32 (VOP3P packed f32).
// R8's counters: issue ~4 cy/wave-instr; R4==R5 proved the compiler
// scalarized all ext_vector math (no v_pk_* emitted). Hand-written VOP3P
// halves the dominant instruction class: per j, 32 scalar fma -> 16 pk_fma.
// (Probe dispatch from R12 removed: isolate the pk change, minimize risk.)
// ---------------------------------------------------------------------------
template <int CHUNK, int R>
__global__ __launch_bounds__(256, 2) void tc_joint(
    const float* __restrict__ z, const float* __restrict__ cj,
    float* __restrict__ jp) {
  __shared__ float lcj[CHUNK * 36];
  const int tid = threadIdx.x;
  const int i0 = blockIdx.x * (256 * R) + tid;
  const int j0 = blockIdx.y * CHUNK;
  const float JMUL = 65535.0f * 8192.0f;
  const float JK   = -SCALE23 * (16.0f * OFFC - BIASF);

  {
    const float4* g4 = (const float4*)(cj + (size_t)j0 * 36);
    float4* l4 = (float4*)lcj;
    for (int t = tid; t < (CHUNK * 36) / 4; t += 256) l4[t] = g4[t];
  }

  f32x2 zv[R][8];
#pragma unroll
  for (int r = 0; r < R; ++r) {
    const float4* zp = (const float4*)(z + (size_t)(i0 + 256 * r) * 16);
#pragma unroll
    for (int q = 0; q < 4; ++q) {
      float4 v = zp[q];
      zv[r][2 * q]     = (f32x2){v.x, v.y};
      zv[r][2 * q + 1] = (f32x2){v.z, v.w};
    }
  }
  // Pin: compiler otherwise sinks z loads into the j-loop (R4 lesson).
#pragma unroll
  for (int r = 0; r < R; ++r)
#pragma unroll
    for (int p = 0; p < 8; ++p) asm volatile("" : "+v"(zv[r][p]));

  float accJ[R];
#pragma unroll
  for (int r = 0; r < R; ++r) accJ[r] = 0.0f;

  __syncthreads();

#pragma unroll 2
  for (int j = 0; j < CHUNK; ++j) {
    const float* cp = lcj + j * 36;
    f32x2 A[8], Bv[8];
#pragma unroll
    for (int t = 0; t < 4; ++t) {  // 8x ds_read_b128
      *(float4*)&A[2 * t]  = *(const float4*)(cp + 4 * t);
      *(float4*)&Bv[2 * t] = *(const float4*)(cp + 16 + 4 * t);
    }
    float Cs = cp[32];             // 1x ds_read_b32
#pragma unroll
    for (int r = 0; r < R; ++r) {
      f32x2 acc = (f32x2){0.0f, 0.0f};
#pragma unroll
      for (int p = 0; p < 8; ++p) {
        f32x2 t2;
        asm("v_pk_fma_f32 %0, %1, %2, %3"
            : "=v"(t2) : "v"(A[p]), "v"(zv[r][p]), "v"(Bv[p]));
        asm("v_pk_fma_f32 %0, %1, %2, %0"
            : "+v"(acc) : "v"(t2), "v"(zv[r][p]));
      }
      float js = (acc.x + acc.y) + Cs;   // S*(sum_l lp2 + 16*OFFC)
      float w = fmaf(js, JMUL, JK);      // 2^23*(sum lp2 + BIASF)
      unsigned u;
      asm("v_cvt_u32_f32 %0, %1" : "=v"(u) : "v"(w));  // neg saturates to 0
      accJ[r] += __uint_as_float(u);
    }
  }

#pragma unroll
  for (int r = 0; r < R; ++r)
    jp[(size_t)blockIdx.y * BB + (size_t)(i0 + 256 * r)] = accJ[r];
}

// ---------------------------------------------------------------------------
// Kernel D: final. Joint-partial sum + table interpolation + logs + fold.
// ---------------------------------------------------------------------------
__global__ __launch_bounds__(256) void final_kernel(
    const float* __restrict__ z, const float* __restrict__ jp,
    const float* __restrict__ table, const float* __restrict__ rp,
    const float* __restrict__ klp, float* __restrict__ out, int nc) {
  __shared__ float ltab[16 * NPTS];  // 64 KB
  const int tid = threadIdx.x;
  const int i = blockIdx.x * 256 + tid;

  for (int t = tid; t < 16 * NPTS; t += 256) ltab[t] = table[t];

  float s0 = 0.0f, s1 = 0.0f, s2 = 0.0f, s3 = 0.0f;
  for (int c = 0; c < nc; c += 4) {
    s0 += jp[(size_t)(c + 0) * BB + i];
    s1 += jp[(size_t)(c + 1) * BB + i];
    s2 += jp[(size_t)(c + 2) * BB + i];
    s3 += jp[(size_t)(c + 3) * BB + i];
  }
  float lg = LOG2((s0 + s1) + (s2 + s3));  // log2 S_joint

  __syncthreads();  // table staged

  const float4* zp = (const float4*)(z + (size_t)i * 16);
  const float SC = (float)(NPTS - 1) / XRANGE;
#pragma unroll
  for (int q = 0; q < 4; ++q) {
    float4 v = zp[q];
    float xs[4] = {v.x, v.y, v.z, v.w};
#pragma unroll
    for (int k = 0; k < 4; ++k) {
      int l = 4 * q + k;
      float t = (xs[k] - XMIN) * SC;
      t = fminf(fmaxf(t, 0.0f), (float)(NPTS - 2) + 0.999f);
      int g = (int)t;
      float f = t - (float)g;
      float m0 = ltab[l * NPTS + g];
      float m1 = ltab[l * NPTS + g + 1];
      lg -= LOG2(fmaf(f, m1 - m0, m0));
    }
  }

  float tval = lg * (LN2_F / (float)BB);
  if (blockIdx.x == 0) {
#pragma unroll
    for (int q = 0; q < 8; ++q) tval += rp[tid + 256 * q];
    tval += klp[tid];
  }

  __syncthreads();  // all gathers done; safe to reuse ltab
#pragma unroll
  for (int off = 32; off; off >>= 1) tval += __shfl_xor(tval, off);
  if ((tid & 63) == 0) ltab[tid >> 6] = tval;
  __syncthreads();
  if (tid == 0) atomicAdd(out, (ltab[0] + ltab[1]) + (ltab[2] + ltab[3]));
}

extern "C" void kernel_launch(void* const* d_in, const int* in_sizes, int n_in,
                              void* d_out, int out_size, void* d_ws, size_t ws_size,
                              hipStream_t stream) {
  const float* data  = (const float*)d_in[0];
  const float* recon = (const float*)d_in[1];
  const float* z     = (const float*)d_in[2];
  const float* zm    = (const float*)d_in[3];
  const float* zlv   = (const float*)d_in[4];
  float* out = (float*)d_out;
  float* ws  = (float*)d_ws;

  const int nc = 128;  // joint chunks: CHUNK=32, grid (4,128) = 512 = 2/CU

  float* cj   = ws + CJ_F;
  float* ct   = ws + CT_F;
  float* rp   = ws + RP_F;
  float* klp  = ws + KLP_F;
  float* tp   = ws + TP_F;
  float* tab  = ws + TAB_F;
  float* jp   = ws + JP_F;

  hipLaunchKernelGGL(prep_recon_kernel, dim3(2048), dim3(256), 0, stream,
                     reinterpret_cast<const float4*>(data),
                     reinterpret_cast<const float4*>(recon),
                     zm, zlv, cj, ct, rp, klp, out);
  hipLaunchKernelGGL(table_build, dim3(32, 16), dim3(256), 0, stream,
                     ct, tp);
  hipLaunchKernelGGL(table_reduce, dim3((16 * NPTS) / 256), dim3(256), 0,
                     stream, tp, tab);
  hipLaunchKernelGGL((tc_joint<32, 4>), dim3(4, 128), dim3(256), 0, stream,
                     z, cj, jp);
  hipLaunchKernelGGL(final_kernel, dim3(BB / 256), dim3(256), 0, stream,
                     z, jp, tab, rp, klp, out, nc);
}